// Round 14
// baseline (189.850 us; speedup 1.0000x reference)
//
#include <hip/hip_runtime.h>
#include <hip/hip_bf16.h>
#include <math.h>

#define Bn 4
#define Sn 512
#define Dn 512
#define DINn 1024
#define Hn 16
#define Pn 64
#define RNn 128
#define DFFn 1368
#define KP2 1408      // w2 K pad / w13T half-stride (BK multiple)
#define BSn (Bn*Sn)
#define CH 64
#define NCH (Sn/CH)   // 8
#define PSTR 6144     // fused proj row stride: [z(1024) | u(1024) | B(2048) | C(2048)]
#define FPAD 2816     // w13T rows: [w1^T pad->1408 | w3^T pad->1408]
#define NSCAN (Bn*NCH*Hn)  // 512 scan blocks
#define NRMS 512      // rmsnorm blocks (4 rows each: 1 row per wave, 4 waves/block)

typedef __attribute__((ext_vector_type(8))) short short8;
typedef __attribute__((ext_vector_type(4))) float f32x4;
typedef __attribute__((ext_vector_type(4))) short short4v;

static __device__ __forceinline__ float bf2f(__hip_bfloat16 v){return __bfloat162float(v);}
static __device__ __forceinline__ __hip_bfloat16 f2bf(float v){return __float2bfloat16(v);}
static __device__ __forceinline__ short f2bfs(float v){ __hip_bfloat16 b=f2bf(v); short s; __builtin_memcpy(&s,&b,2); return s; }
static __device__ __forceinline__ float bfs2f(short s){ __hip_bfloat16 b; __builtin_memcpy(&b,&s,2); return bf2f(b); }

// XCD-aware block swizzle (T1): grid must be a multiple of 8; q = nwg/8.
static __device__ __forceinline__ int xcd_swz(int bid, int q) {
  return (bid & 7) * q + (bid >> 3);
}

// async global->LDS, 16B per lane. LDS dest is wave-uniform base + lane*16 (HW).
typedef const __attribute__((address_space(1))) unsigned int* gas1_u32p;
typedef __attribute__((address_space(3))) unsigned int* gas3_u32p;
static __device__ __forceinline__ void gl_lds16(const void* g, void* l) {
  __builtin_amdgcn_global_load_lds((gas1_u32p)g, (gas3_u32p)l, 16, 0, 0);
}

// ---------------- transpose job table + tile body (64x64 tiles, float4 loads) ----------------
struct T8 {
  const float* src[8];
  const float* svec[8];     // optional per-orig-row scale (n2w fold), nullptr = 1
  __hip_bfloat16* dst[8];
  int Rr[8], Cc[8], RrPad[8], CcPad[8], gw[8];
  int start[9];
};

static __device__ __forceinline__ void transpose_tile(const T8& d, int bid, int t,
                                                      float (*tile)[65]) {
  int i = 0;
#pragma unroll
  for (int k = 1; k < 8; ++k) if (bid >= d.start[k]) i = k;
  int rel = bid - d.start[i];
  int gx = rel % d.gw[i], gy = rel / d.gw[i];
  const float* in = d.src[i];
  const float* sv = d.svec[i];
  __hip_bfloat16* out = d.dst[i];
  int Rr = d.Rr[i], Cc = d.Cc[i], RrPad = d.RrPad[i], CcPad = d.CcPad[i];
  int tx = t & 15, ty = t >> 4;
#pragma unroll
  for (int i4 = 0; i4 < 4; ++i4) {
    int r = gy * 64 + ty + i4 * 16;
    int c0 = gx * 64 + tx * 4;
    f32x4 v = (f32x4){0.f, 0.f, 0.f, 0.f};
    if (r < Rr && c0 + 3 < Cc) v = *(const f32x4*)(in + (size_t)r * Cc + c0);
    tile[ty + i4 * 16][tx * 4 + 0] = v[0];
    tile[ty + i4 * 16][tx * 4 + 1] = v[1];
    tile[ty + i4 * 16][tx * 4 + 2] = v[2];
    tile[ty + i4 * 16][tx * 4 + 3] = v[3];
  }
  __syncthreads();
#pragma unroll
  for (int i4 = 0; i4 < 4; ++i4) {
    int r2 = gx * 64 + ty + i4 * 16;
    int c2 = gy * 64 + tx * 4;
    if (r2 < CcPad && c2 + 3 < RrPad) {
      int k = ty + i4 * 16;
      float s0 = sv ? sv[c2 + 0] : 1.f;
      float s1 = sv ? sv[c2 + 1] : 1.f;
      float s2 = sv ? sv[c2 + 2] : 1.f;
      float s3 = sv ? sv[c2 + 3] : 1.f;
      short4v o;
      o.x = f2bfs(tile[tx * 4 + 0][k] * s0);
      o.y = f2bfs(tile[tx * 4 + 1][k] * s1);
      o.z = f2bfs(tile[tx * 4 + 2][k] * s2);
      o.w = f2bfs(tile[tx * 4 + 3][k] * s3);
      *(short4v*)((short*)out + (size_t)r2 * RrPad + c2) = o;
    }
  }
}

// ---------------- prep: transposes + wave-per-row rmsnorm1+dt + zero(rs) ---------------------
__global__ __launch_bounds__(256) void prep_kernel(
    T8 d, const float* __restrict__ x, const float* __restrict__ w,
    const float* __restrict__ mask, const float* __restrict__ Wdt,
    const float* __restrict__ dtb, const float* __restrict__ Alog,
    __hip_bfloat16* __restrict__ outb, float* __restrict__ dt,
    float* __restrict__ la, float* __restrict__ rs, int tstart) {
  __shared__ __align__(16) char smem[40960];
  int bid = blockIdx.x, t = threadIdx.x;
  if (bid < tstart) {
    transpose_tile(d, bid, t, (float(*)[65])smem);
  } else if (bid - tstart < NRMS) {
    float* wdtS = (float*)smem;                    // [512][16] f32
    float* xsS  = (float*)(smem + 32768);          // [4][512] f32 (per-wave exclusive)
#pragma unroll
    for (int i = 0; i < 8; ++i) {
      int idx = t + i * 256;
      *(f32x4*)&wdtS[idx * 4] = *(const f32x4*)&Wdt[idx * 4];
    }
    __syncthreads();
    int wv = t >> 6, lane = t & 63;
    int row = (bid - tstart) * 4 + wv;
    const float* xr = x + (size_t)row * Dn;
    f32x4 v0 = *(const f32x4*)(xr + lane * 4);
    f32x4 v1 = *(const f32x4*)(xr + 256 + lane * 4);
    float ss = v0[0]*v0[0] + v0[1]*v0[1] + v0[2]*v0[2] + v0[3]*v0[3]
             + v1[0]*v1[0] + v1[1]*v1[1] + v1[2]*v1[2] + v1[3]*v1[3];
#pragma unroll
    for (int o = 32; o > 0; o >>= 1) ss += __shfl_xor(ss, o);
    float sc = rsqrtf(ss * (1.f / Dn) + 1e-6f) * mask[row];
    f32x4 w0 = *(const f32x4*)(w + lane * 4);
    f32x4 w1 = *(const f32x4*)(w + 256 + lane * 4);
    f32x4 o0, o1;
#pragma unroll
    for (int j = 0; j < 4; ++j) { o0[j] = v0[j] * sc * w0[j]; o1[j] = v1[j] * sc * w1[j]; }
    short4v b0, b1;
    b0.x = f2bfs(o0[0]); b0.y = f2bfs(o0[1]); b0.z = f2bfs(o0[2]); b0.w = f2bfs(o0[3]);
    b1.x = f2bfs(o1[0]); b1.y = f2bfs(o1[1]); b1.z = f2bfs(o1[2]); b1.w = f2bfs(o1[3]);
    *(short4v*)((short*)outb + (size_t)row * Dn + lane * 4) = b0;
    *(short4v*)((short*)outb + (size_t)row * Dn + 256 + lane * 4) = b1;
    *(f32x4*)&xsS[wv * 512 + lane * 4] = o0;
    *(f32x4*)&xsS[wv * 512 + 256 + lane * 4] = o1;
    int h = lane >> 2, j = lane & 3;
    float s = 0.f;
#pragma unroll 8
    for (int kk = 0; kk < 128; ++kk) {
      int k = j + kk * 4;
      s = fmaf(xsS[wv * 512 + k], wdtS[k * Hn + h], s);
    }
    s += __shfl_down(s, 2, 4);
    s += __shfl_down(s, 1, 4);
    if (j == 0) {
      float v = s + dtb[h];
      float sp = (v > 20.f) ? v : log1pf(expf(v));
      float Ah = expf(Alog[h]);
      dt[(size_t)row * Hn + h] = sp;
      la[(size_t)row * Hn + h] = -Ah * sp;
    }
  } else {
    *(f32x4*)&rs[t * 8]     = (f32x4){0.f, 0.f, 0.f, 0.f};
    *(f32x4*)&rs[t * 8 + 4] = (f32x4){0.f, 0.f, 0.f, 0.f};
  }
}

// ---------------- GEMM 128x128, BK=32, gl_lds staging, XCD swizzle (proj) --------------------
__global__ __launch_bounds__(256) void gemm_kernel(
    const __hip_bfloat16* __restrict__ A, const __hip_bfloat16* __restrict__ BT,
    __hip_bfloat16* __restrict__ C, int M, int N, int K) {
  __shared__ short As[2][4096];
  __shared__ short Bs[2][4096];
  int mblocks = M >> 7;
  int wg = xcd_swz(blockIdx.x, (int)gridDim.x >> 3);
  int m0 = (wg % mblocks) * 128, n0 = (wg / mblocks) * 128;
  int t = threadIdx.x;
  int lane = t & 63, wv = t >> 6;
  int wm = (wv & 1) * 64, wn = (wv >> 1) * 64;
  f32x4 acc[4][4];
#pragma unroll
  for (int i = 0; i < 4; ++i)
#pragma unroll
    for (int j = 0; j < 4; ++j) acc[i][j] = (f32x4){0.f, 0.f, 0.f, 0.f};
  const short* Ag = (const short*)A;
  const short* Bg = (const short*)BT;
  int r0 = t >> 2, p = t & 3;
  int q0 = (p - (r0 >> 1)) & 3;
  int r1 = r0 + 64;
  int q1 = (p - (r1 >> 1)) & 3;
  const short* Asrc0 = Ag + (size_t)(m0 + r0) * K + 8 * q0;
  const short* Asrc1 = Ag + (size_t)(m0 + r1) * K + 8 * q1;
  const short* Bsrc0 = Bg + (size_t)(n0 + r0) * K + 8 * q0;
  const short* Bsrc1 = Bg + (size_t)(n0 + r1) * K + 8 * q1;
  int fr = lane & 15, fq = lane >> 4;
  int kTiles = K >> 5;
  auto stage = [&](int buf, int k0) {
    gl_lds16(Asrc0 + k0, &As[buf][wv * 512]);
    gl_lds16(Asrc1 + k0, &As[buf][2048 + wv * 512]);
    gl_lds16(Bsrc0 + k0, &Bs[buf][wv * 512]);
    gl_lds16(Bsrc1 + k0, &Bs[buf][2048 + wv * 512]);
  };
  auto domfma = [&](int buf) {
    short8 af[4], bfr[4];
#pragma unroll
    for (int i = 0; i < 4; ++i) {
      int rr = wm + i * 16 + fr;
      af[i] = *(const short8*)&As[buf][rr * 32 + (((rr >> 1) + fq) & 3) * 8];
    }
#pragma unroll
    for (int i = 0; i < 4; ++i) {
      int rr = wn + i * 16 + fr;
      bfr[i] = *(const short8*)&Bs[buf][rr * 32 + (((rr >> 1) + fq) & 3) * 8];
    }
#pragma unroll
    for (int mi = 0; mi < 4; ++mi)
#pragma unroll
      for (int ni = 0; ni < 4; ++ni)
        acc[mi][ni] = __builtin_amdgcn_mfma_f32_16x16x32_bf16(af[mi], bfr[ni], acc[mi][ni], 0, 0, 0);
  };
  stage(0, 0);
  for (int kt = 0; kt < kTiles; ++kt) {
    int buf = kt & 1;
    __syncthreads();
    if (kt + 1 < kTiles) stage(buf ^ 1, (kt + 1) << 5);
    domfma(buf);
  }
  int fq4 = (lane >> 4) * 4;
#pragma unroll
  for (int mi = 0; mi < 4; ++mi)
#pragma unroll
    for (int ni = 0; ni < 4; ++ni) {
      int col = n0 + wn + ni * 16 + fr;
      if (col < N) {
        int rowb = m0 + wm + mi * 16 + fq4;
#pragma unroll
        for (int r = 0; r < 4; ++r)
          C[(size_t)(rowb + r) * N + col] = f2bf(acc[mi][ni][r]);
      }
    }
}

// ---------------- GEMM 64x64, BK=64, gl_lds staging + slot swizzle; fused epilogues ----------
// LDS per matrix: linear [64][64] bf16 (128B rows). Physical 16B slot p of row r holds
// logical col-block q = (p - r) & 7 (source pre-swizzled). Read group (16 rows, same q)
// spreads over all 8 slots twice -> free 2-way. MODE1: +row-sumsq atomics + bf16 copy.
template <int MODE>
__global__ __launch_bounds__(256) void gemm64_ep_kernel(
    const __hip_bfloat16* __restrict__ A, const __hip_bfloat16* __restrict__ BT,
    const float* __restrict__ aux, const float* __restrict__ mask,
    float* __restrict__ out, __hip_bfloat16* __restrict__ outb,
    float* __restrict__ rs, int M, int N, int K) {
  __shared__ short As[2][4096];
  __shared__ short Bs[2][4096];
  int mblocks = M >> 6;
  int wg = xcd_swz(blockIdx.x, (int)gridDim.x >> 3);
  int m0 = (wg % mblocks) * 64, n0 = (wg / mblocks) * 64;
  int t = threadIdx.x;
  int lane = t & 63, wv = t >> 6;
  int wm = (wv & 1) * 32, wn = (wv >> 1) * 32;
  f32x4 acc[2][2];
#pragma unroll
  for (int i = 0; i < 2; ++i)
#pragma unroll
    for (int j = 0; j < 2; ++j) acc[i][j] = (f32x4){0.f, 0.f, 0.f, 0.f};
  const short* Ag = (const short*)A;
  const short* Bg = (const short*)BT;
  // staging: issue0 rows 0..31 (thread t -> row t>>3, slot t&7), issue1 rows 32..63
  int r0 = t >> 3, p = t & 7;
  int q0 = (p - r0) & 7;
  int r1 = r0 + 32;
  int q1 = (p - r1) & 7;
  const short* Asrc0 = Ag + (size_t)(m0 + r0) * K + q0 * 8;
  const short* Asrc1 = Ag + (size_t)(m0 + r1) * K + q1 * 8;
  const short* Bsrc0 = Bg + (size_t)(n0 + r0) * K + q0 * 8;
  const short* Bsrc1 = Bg + (size_t)(n0 + r1) * K + q1 * 8;
  int fr = lane & 15, fh = lane >> 4;   // fh = logical 8-col group within 32-col K-slice
  int kTiles = K >> 6;
  auto stage = [&](int buf, int k0) {
    gl_lds16(Asrc0 + k0, &As[buf][wv * 512]);
    gl_lds16(Asrc1 + k0, &As[buf][2048 + wv * 512]);
    gl_lds16(Bsrc0 + k0, &Bs[buf][wv * 512]);
    gl_lds16(Bsrc1 + k0, &Bs[buf][2048 + wv * 512]);
  };
  auto domfma = [&](int buf) {
#pragma unroll
    for (int kk = 0; kk < 2; ++kk) {
      short8 af[2], bfr[2];
#pragma unroll
      for (int i = 0; i < 2; ++i) {
        int rr = wm + i * 16 + fr;
        af[i] = *(const short8*)&As[buf][rr * 64 + (((rr + kk * 4 + fh) & 7) * 8)];
      }
#pragma unroll
      for (int i = 0; i < 2; ++i) {
        int rr = wn + i * 16 + fr;
        bfr[i] = *(const short8*)&Bs[buf][rr * 64 + (((rr + kk * 4 + fh) & 7) * 8)];
      }
#pragma unroll
      for (int mi = 0; mi < 2; ++mi)
#pragma unroll
        for (int ni = 0; ni < 2; ++ni)
          acc[mi][ni] = __builtin_amdgcn_mfma_f32_16x16x32_bf16(af[mi], bfr[ni], acc[mi][ni], 0, 0, 0);
    }
  };
  stage(0, 0);
  for (int kt = 0; kt < kTiles; ++kt) {
    int buf = kt & 1;
    __syncthreads();
    if (kt + 1 < kTiles) stage(buf ^ 1, (kt + 1) << 6);
    domfma(buf);
  }
  int fq4 = (lane >> 4) * 4;
  float rsum[2][4];
#pragma unroll
  for (int mi = 0; mi < 2; ++mi)
#pragma unroll
    for (int r = 0; r < 4; ++r) rsum[mi][r] = 0.f;
#pragma unroll
  for (int mi = 0; mi < 2; ++mi)
#pragma unroll
    for (int ni = 0; ni < 2; ++ni) {
      int col = n0 + wn + ni * 16 + fr;
#pragma unroll
      for (int r = 0; r < 4; ++r) {
        int row = m0 + wm + mi * 16 + fq4 + r;
        float m = mask[row];
        size_t a = (size_t)row * N + col;
        float v = acc[mi][ni][r];
        if (MODE == 1) {
          float ov = aux[a] + v * m;
          out[a] = ov;
          outb[a] = f2bf(ov);
          rsum[mi][r] += ov * ov;
        } else {
          out[a] = (aux[a] + v) * m;
        }
      }
    }
  if (MODE == 1) {
#pragma unroll
    for (int mi = 0; mi < 2; ++mi)
#pragma unroll
      for (int r = 0; r < 4; ++r) {
        float s = rsum[mi][r];
#pragma unroll
        for (int o = 8; o > 0; o >>= 1) s += __shfl_xor(s, o);
        if ((lane & 15) == 0) {
          int row = m0 + wm + mi * 16 + fq4 + r;
          atomicAdd(&rs[row], s);
        }
      }
  }
}

// ---------------- fused FFN GEMM 64x64: gl_lds staging, symmetric w13T, silu-gate ------------
__global__ __launch_bounds__(256) void gemm64g_kernel(
    const __hip_bfloat16* __restrict__ A, const float* __restrict__ rs,
    const __hip_bfloat16* __restrict__ BT, __hip_bfloat16* __restrict__ G,
    int M, int K) {
  __shared__ short As[2][4096];
  __shared__ short B1s[2][4096];
  __shared__ short B3s[2][4096];
  __shared__ float ssc[64];
  int mblocks = M >> 6;
  int wg = xcd_swz(blockIdx.x, (int)gridDim.x >> 3);
  int m0 = (wg % mblocks) * 64, n0 = (wg / mblocks) * 64;
  int t = threadIdx.x;
  int lane = t & 63, wv = t >> 6;
  int wm = (wv & 1) * 32, wn = (wv >> 1) * 32;
  f32x4 acc1[2][2], acc3[2][2];
#pragma unroll
  for (int i = 0; i < 2; ++i)
#pragma unroll
    for (int j = 0; j < 2; ++j) {
      acc1[i][j] = (f32x4){0.f, 0.f, 0.f, 0.f};
      acc3[i][j] = (f32x4){0.f, 0.f, 0.f, 0.f};
    }
  const short* Ag = (const short*)A;
  const short* Bg = (const short*)BT;
  int r0 = t >> 3, p = t & 7;
  int q0 = (p - r0) & 7;
  int r1 = r0 + 32;
  int q1 = (p - r1) & 7;
  const short* Asrc0  = Ag + (size_t)(m0 + r0) * K + q0 * 8;
  const short* Asrc1  = Ag + (size_t)(m0 + r1) * K + q1 * 8;
  const short* B1src0 = Bg + (size_t)(n0 + r0) * K + q0 * 8;
  const short* B1src1 = Bg + (size_t)(n0 + r1) * K + q1 * 8;
  const short* B3src0 = Bg + (size_t)(KP2 + n0 + r0) * K + q0 * 8;
  const short* B3src1 = Bg + (size_t)(KP2 + n0 + r1) * K + q1 * 8;
  int fr = lane & 15, fh = lane >> 4;
  int kTiles = K >> 6;
  if (t < 64) ssc[t] = rsqrtf(rs[m0 + t] * (1.f / Dn) + 1e-6f);
  auto stage = [&](int buf, int k0) {
    gl_lds16(Asrc0 + k0, &As[buf][wv * 512]);
    gl_lds16(Asrc1 + k0, &As[buf][2048 + wv * 512]);
    gl_lds16(B1src0 + k0, &B1s[buf][wv * 512]);
    gl_lds16(B1src1 + k0, &B1s[buf][2048 + wv * 512]);
    gl_lds16(B3src0 + k0, &B3s[buf][wv * 512]);
    gl_lds16(B3src1 + k0, &B3s[buf][2048 + wv * 512]);
  };
  auto domfma = [&](int buf) {
#pragma unroll
    for (int kk = 0; kk < 2; ++kk) {
      short8 af[2], b1f[2], b3f[2];
#pragma unroll
      for (int i = 0; i < 2; ++i) {
        int rr = wm + i * 16 + fr;
        af[i] = *(const short8*)&As[buf][rr * 64 + (((rr + kk * 4 + fh) & 7) * 8)];
      }
#pragma unroll
      for (int i = 0; i < 2; ++i) {
        int rr = wn + i * 16 + fr;
        int so = rr * 64 + (((rr + kk * 4 + fh) & 7) * 8);
        b1f[i] = *(const short8*)&B1s[buf][so];
        b3f[i] = *(const short8*)&B3s[buf][so];
      }
#pragma unroll
      for (int mi = 0; mi < 2; ++mi)
#pragma unroll
        for (int ni = 0; ni < 2; ++ni) {
          acc1[mi][ni] = __builtin_amdgcn_mfma_f32_16x16x32_bf16(af[mi], b1f[ni], acc1[mi][ni], 0, 0, 0);
          acc3[mi][ni] = __builtin_amdgcn_mfma_f32_16x16x32_bf16(af[mi], b3f[ni], acc3[mi][ni], 0, 0, 0);
        }
    }
  };
  stage(0, 0);
  for (int kt = 0; kt < kTiles; ++kt) {
    int buf = kt & 1;
    __syncthreads();
    if (kt + 1 < kTiles) stage(buf ^ 1, (kt + 1) << 6);
    domfma(buf);
  }
  int fq4 = (lane >> 4) * 4;
#pragma unroll
  for (int mi = 0; mi < 2; ++mi)
#pragma unroll
    for (int ni = 0; ni < 2; ++ni) {
      int col = n0 + wn + ni * 16 + fr;
#pragma unroll
      for (int r = 0; r < 4; ++r) {
        int rloc = wm + mi * 16 + fq4 + r;
        float scl = ssc[rloc];
        float h1v = acc1[mi][ni][r] * scl;
        float sil = h1v / (1.f + __expf(-h1v));
        float g = sil * (acc3[mi][ni][r] * scl);
        G[(size_t)(m0 + rloc) * KP2 + col] = f2bf(g);
      }
    }
}

// ---------------- chunk_state: B,u -> S (transposed [p][rn]) + ecL ---------------------------
__global__ __launch_bounds__(256) void chunk_state_kernel(
    const __hip_bfloat16* __restrict__ P, const float* __restrict__ dt,
    const float* __restrict__ la, __hip_bfloat16* __restrict__ Sbuf,
    float* __restrict__ ecL) {
  int id = blockIdx.x;
  int h = id & 15, c = (id >> 4) & 7, b = id >> 7;
  int t = threadIdx.x, lane = t & 63, wv = t >> 6;
  __shared__ __align__(16) char smem[45824];
  short* sB   = (short*)smem;                 // [64][136]
  short* sUD  = (short*)(smem + 17408);       // [64*72] u*dt transposed [p][s]
  short* sBwT = (short*)(smem + 26624);       // [128][72] weighted B^T [rn][s]
  float* scum = (float*)(smem + 45056);
  float* sws  = scum + 64;
  float* sdt  = sws + 64;
  int row0 = b * Sn + c * CH;
  const short* Pb = (const short*)P;
#pragma unroll
  for (int i = 0; i < 4; ++i) {
    int idx = t + i * 256;
    int r = idx >> 4, kk = (idx & 15) * 8;
    *(short8*)&sB[r * 136 + kk] = *(const short8*)(Pb + (size_t)(row0 + r) * PSTR + 2048 + h * 128 + kk);
  }
  if (t < 64) { sdt[t] = dt[(size_t)(row0 + t) * Hn + h]; scum[t] = la[(size_t)(row0 + t) * Hn + h]; }
  __syncthreads();
  if (wv == 0) {
    float v = scum[lane];
#pragma unroll
    for (int o = 1; o < 64; o <<= 1) { float n = __shfl_up(v, o); if (lane >= o) v += n; }
    float c63 = __shfl(v, 63);
    sws[lane] = __expf(c63 - v);
    if (lane == 0) ecL[(b * NCH + c) * Hn + h] = __expf(c63);
  }
#pragma unroll
  for (int i = 0; i < 2; ++i) {
    int idx = t + i * 256;
    int s = idx >> 3, pc = (idx & 7) * 8;
    short8 uv = *(const short8*)(Pb + (size_t)(row0 + s) * PSTR + 1024 + h * 64 + pc);
    float dv = sdt[s];
#pragma unroll
    for (int j = 0; j < 8; ++j) sUD[(pc + j) * 72 + s] = f2bfs(bfs2f(uv[j]) * dv);
  }
  __syncthreads();
#pragma unroll
  for (int i = 0; i < 32; ++i) {
    int idx = t + i * 256;
    int rn = idx >> 6, s = idx & 63;
    sBwT[rn * 72 + s] = f2bfs(bfs2f(sB[s * 136 + rn]) * sws[s]);
  }
  __syncthreads();
  int fr = lane & 15, fq = (lane >> 4) * 8, q4 = (lane >> 4) * 4;
#pragma unroll
  for (int mt0 = 0; mt0 < 2; ++mt0) {
    int mt = wv * 2 + mt0;
    short8 ab[2];
#pragma unroll
    for (int k = 0; k < 2; ++k) ab[k] = *(short8*)&sBwT[(16 * mt + fr) * 72 + k * 32 + fq];
#pragma unroll
    for (int j = 0; j < 4; ++j) {
      f32x4 acc = (f32x4){0.f, 0.f, 0.f, 0.f};
#pragma unroll
      for (int k = 0; k < 2; ++k) {
        short8 bf = *(short8*)&sUD[(16 * j + fr) * 72 + k * 32 + fq];
        acc = __builtin_amdgcn_mfma_f32_16x16x32_bf16(ab[k], bf, acc, 0, 0, 0);
      }
      int pp = 16 * j + fr;
      int rn0 = 16 * mt + q4;
      short4v o;
      o.x = f2bfs(acc[0]); o.y = f2bfs(acc[1]); o.z = f2bfs(acc[2]); o.w = f2bfs(acc[3]);
      *(short4v*)&((short*)Sbuf)[((size_t)((b * NCH + c) * Hn + h) * 64 + pp) * 128 + rn0] = o;
    }
  }
}

// ---------------- intra + cross-chunk prefix + inter + gate (single-pass, ys in regs) --------
__global__ __launch_bounds__(256) void intra_inter_gate_kernel(
    const __hip_bfloat16* __restrict__ P, const float* __restrict__ dt,
    const float* __restrict__ la, const __hip_bfloat16* __restrict__ Sbuf,
    const float* __restrict__ ecL, const float* __restrict__ Dsk,
    __hip_bfloat16* __restrict__ y2b) {
  int id = blockIdx.x;
  int h = id & 15, c = (id >> 4) & 7, b = id >> 7;
  int t = threadIdx.x, lane = t & 63, wv = t >> 6;
  __shared__ __align__(16) char smem[54016];
  short* sCB = (short*)smem;
  short* sB  = (short*)(smem + 17408);
  short* sUD = (short*)(smem + 34816);
  short* sG  = (short*)(smem + 44032);
  short* sHt = (short*)(smem + 34816);        // aliases sUD+sG after ys
  short* sz  = sB;                            // [64][64] bytes [17408,25600) -- dead sB
  short* su  = sB + 4096;                     // [64][64] bytes [25600,33792) -- dead sB
  float* scum = (float*)(smem + 53248);
  float* sdt  = scum + 64;
  int row0 = b * Sn + c * CH;
  const short* Pb = (const short*)P;
#pragma unroll
  for (int i = 0; i < 4; ++i) {
    int idx = t + i * 256;
    int r = idx >> 4, kk = (idx & 15) * 8;
    *(short8*)&sCB[r * 136 + kk] = *(const short8*)(Pb + (size_t)(row0 + r) * PSTR + 4096 + h * 128 + kk);
    *(short8*)&sB [r * 136 + kk] = *(const short8*)(Pb + (size_t)(row0 + r) * PSTR + 2048 + h * 128 + kk);
  }
  if (t < 64) { sdt[t] = dt[(size_t)(row0 + t) * Hn + h]; scum[t] = la[(size_t)(row0 + t) * Hn + h]; }
  __syncthreads();
  if (wv == 0) {
    float v = scum[lane];
#pragma unroll
    for (int o = 1; o < 64; o <<= 1) { float n = __shfl_up(v, o); if (lane >= o) v += n; }
    scum[lane] = v;
  }
#pragma unroll
  for (int i = 0; i < 2; ++i) {
    int idx = t + i * 256;
    int s = idx >> 3, pc = (idx & 7) * 8;
    short8 uv = *(const short8*)(Pb + (size_t)(row0 + s) * PSTR + 1024 + h * 64 + pc);
    float dv = sdt[s];
#pragma unroll
    for (int j = 0; j < 8; ++j) sUD[(pc + j) * 72 + s] = f2bfs(bfs2f(uv[j]) * dv);
  }
  __syncthreads();
  int fr = lane & 15, fq = (lane >> 4) * 8, q4 = (lane >> 4) * 4;
  {
    short8 af[4];
#pragma unroll
    for (int k = 0; k < 4; ++k) af[k] = *(short8*)&sCB[(16 * wv + fr) * 136 + k * 32 + fq];
#pragma unroll
    for (int j = 0; j < 4; ++j) {
      f32x4 acc = (f32x4){0.f, 0.f, 0.f, 0.f};
#pragma unroll
      for (int k = 0; k < 4; ++k) {
        short8 bf = *(short8*)&sB[(16 * j + fr) * 136 + k * 32 + fq];
        acc = __builtin_amdgcn_mfma_f32_16x16x32_bf16(af[k], bf, acc, 0, 0, 0);
      }
      int ss = 16 * j + fr;
      float cs = scum[ss];
#pragma unroll
      for (int r = 0; r < 4; ++r) {
        int tt = 16 * wv + q4 + r;
        float w = (ss <= tt) ? __expf(scum[tt] - cs) : 0.f;
        sG[tt * 72 + ss] = f2bfs(acc[r] * w);
      }
    }
  }
  __syncthreads();
  f32x4 ysr[4];
  {
    short8 ag[2];
#pragma unroll
    for (int k = 0; k < 2; ++k) ag[k] = *(short8*)&sG[(16 * wv + fr) * 72 + k * 32 + fq];
#pragma unroll
    for (int j = 0; j < 4; ++j) {
      f32x4 acc = (f32x4){0.f, 0.f, 0.f, 0.f};
#pragma unroll
      for (int k = 0; k < 2; ++k) {
        short8 bf = *(short8*)&sUD[(16 * j + fr) * 72 + k * 32 + fq];
        acc = __builtin_amdgcn_mfma_f32_16x16x32_bf16(ag[k], bf, acc, 0, 0, 0);
      }
      ysr[j] = acc;
    }
  }
#pragma unroll
  for (int i = 0; i < 2; ++i) {
    int idx = t + i * 256;
    int r = idx >> 3, pc = (idx & 7) * 8;
    *(short8*)&sz[r * 64 + pc] = *(const short8*)(Pb + (size_t)(row0 + r) * PSTR + h * 64 + pc);
    *(short8*)&su[r * 64 + pc] = *(const short8*)(Pb + (size_t)(row0 + r) * PSTR + 1024 + h * 64 + pc);
  }
  float hacc[32];
#pragma unroll
  for (int jj = 0; jj < 32; ++jj) hacc[jj] = 0.f;
  if (c > 0) {
    const short* Sb = (const short*)Sbuf;
    float wrun = 1.f;
    for (int cp = c - 1; cp >= 0; --cp) {
      size_t base = ((size_t)((b * NCH + cp) * Hn + h)) * 8192 + (size_t)t * 32;
#pragma unroll
      for (int v4 = 0; v4 < 4; ++v4) {
        short8 sv = *(const short8*)(Sb + base + v4 * 8);
#pragma unroll
        for (int jj = 0; jj < 8; ++jj)
          hacc[v4 * 8 + jj] = fmaf(wrun, bfs2f(sv[jj]), hacc[v4 * 8 + jj]);
      }
      wrun *= ecL[(size_t)((b * NCH + cp) * Hn + h)];
    }
  }
  __syncthreads();
  if (c > 0) {
    int pp = t >> 2, rn0 = (t & 3) * 32;
#pragma unroll
    for (int v4 = 0; v4 < 4; ++v4) {
      short8 o;
#pragma unroll
      for (int jj = 0; jj < 8; ++jj) o[jj] = f2bfs(hacc[v4 * 8 + jj]);
      *(short8*)&sHt[pp * 136 + rn0 + v4 * 8] = o;
    }
  }
  __syncthreads();
  f32x4 acc[4];
#pragma unroll
  for (int j = 0; j < 4; ++j) acc[j] = (f32x4){0.f, 0.f, 0.f, 0.f};
  if (c > 0) {
    short8 af[4];
#pragma unroll
    for (int k = 0; k < 4; ++k) af[k] = *(short8*)&sCB[(16 * wv + fr) * 136 + k * 32 + fq];
#pragma unroll
    for (int j = 0; j < 4; ++j)
#pragma unroll
      for (int k = 0; k < 4; ++k) {
        short8 bf = *(short8*)&sHt[(16 * j + fr) * 136 + k * 32 + fq];
        acc[j] = __builtin_amdgcn_mfma_f32_16x16x32_bf16(af[k], bf, acc[j], 0, 0, 0);
      }
  }
  float dsk = Dsk[h];
#pragma unroll
  for (int j = 0; j < 4; ++j) {
    int col = 16 * j + fr;
#pragma unroll
    for (int r = 0; r < 4; ++r) {
      int tt = 16 * wv + q4 + r;
      size_t a = (size_t)(row0 + tt) * DINn + h * 64 + col;
      float val = ysr[j][r];
      if (c > 0) val += __expf(scum[tt]) * acc[j][r];
      float uu = bfs2f(su[tt * 64 + col]);
      float zz = bfs2f(sz[tt * 64 + col]);
      float sil = zz / (1.f + __expf(-zz));
      y2b[a] = f2bf((val + uu * dsk) * sil);
    }
  }
}

extern "C" void kernel_launch(void* const* d_in, const int* in_sizes, int n_in,
                              void* d_out, int out_size, void* d_ws, size_t ws_size,
                              hipStream_t stream) {
  const float* x    = (const float*)d_in[0];
  const float* mask = (const float*)d_in[1];
  const float* n1w  = (const float*)d_in[2];
  const float* n2w  = (const float*)d_in[3];
  const float* Wz   = (const float*)d_in[4];
  const float* Wx   = (const float*)d_in[5];
  const float* Wb   = (const float*)d_in[6];
  const float* Wc   = (const float*)d_in[7];
  const float* Wdt  = (const float*)d_in[8];
  const float* dtb  = (const float*)d_in[9];
  const float* Alog = (const float*)d_in[10];
  const float* Dsk  = (const float*)d_in[11];
  const float* Wout = (const float*)d_in[12];
  const float* w1   = (const float*)d_in[13];
  const float* w2   = (const float*)d_in[14];
  const float* w3   = (const float*)d_in[15];

  char* ws = (char*)d_ws;
  size_t off = 0;
  auto alloc = [&](size_t bytes) {
    char* p = ws + off;
    off += (bytes + 255) & ~(size_t)255;
    return p;
  };
  __hip_bfloat16* xnb = (__hip_bfloat16*)alloc((size_t)BSn * Dn * 2);
  __hip_bfloat16* P = (__hip_bfloat16*)alloc((size_t)BSn * PSTR * 2);
  float* dt  = (float*)alloc((size_t)BSn * Hn * 4);
  float* la  = (float*)alloc((size_t)BSn * Hn * 4);
  float* ecL = (float*)alloc((size_t)Bn * NCH * Hn * 4);
  float* rs  = (float*)alloc((size_t)BSn * 4);
  __hip_bfloat16* WallT = (__hip_bfloat16*)alloc((size_t)PSTR * Dn * 2);   // [z|u|B|C]^T
  __hip_bfloat16* WoutT = (__hip_bfloat16*)alloc((size_t)Dn * DINn * 2);
  __hip_bfloat16* w13T  = (__hip_bfloat16*)alloc((size_t)FPAD * Dn * 2);   // [w1^T|pad | w3^T|pad]
  __hip_bfloat16* w2T   = (__hip_bfloat16*)alloc((size_t)Dn * KP2 * 2);    // K-pad 1408
  char* arena = alloc(23200000);
  __hip_bfloat16* Sbuf = (__hip_bfloat16*)arena;                  // 8.4 MB, dead after intra_inter
  __hip_bfloat16* y2b  = (__hip_bfloat16*)(arena + 16777216);     // 4.2 MB
  float* xres          = (float*)arena;                            // 4 MB, aliases Sbuf (after)
  __hip_bfloat16* gatedb = (__hip_bfloat16*)(arena + 4194304);     // 5.8 MB
  __hip_bfloat16* xresb  = (__hip_bfloat16*)(arena + 20971520);    // 2 MB bf16 residual

  // -------- transpose job table (64x64 tiles) --------
  T8 td;
  for (int i = 0; i < 8; ++i) td.svec[i] = nullptr;
  td.src[0] = Wz;   td.dst[0] = WallT;                      td.Rr[0] = 512;  td.Cc[0] = 1024; td.RrPad[0] = 512;  td.CcPad[0] = 1024;
  td.src[1] = Wx;   td.dst[1] = WallT + (size_t)1024 * 512; td.Rr[1] = 512;  td.Cc[1] = 1024; td.RrPad[1] = 512;  td.CcPad[1] = 1024;
  td.src[2] = Wb;   td.dst[2] = WallT + (size_t)2048 * 512; td.Rr[2] = 512;  td.Cc[2] = 2048; td.RrPad[2] = 512;  td.CcPad[2] = 2048;
  td.src[3] = Wc;   td.dst[3] = WallT + (size_t)4096 * 512; td.Rr[3] = 512;  td.Cc[3] = 2048; td.RrPad[3] = 512;  td.CcPad[3] = 2048;
  td.src[4] = Wout; td.dst[4] = WoutT;                      td.Rr[4] = 1024; td.Cc[4] = 512;  td.RrPad[4] = 1024; td.CcPad[4] = 512;
  td.src[5] = w1;   td.dst[5] = w13T;                       td.Rr[5] = 512;  td.Cc[5] = 1368; td.RrPad[5] = 512;  td.CcPad[5] = KP2;
  td.src[6] = w3;   td.dst[6] = w13T + (size_t)KP2 * 512;   td.Rr[6] = 512;  td.Cc[6] = 1368; td.RrPad[6] = 512;  td.CcPad[6] = KP2;
  td.src[7] = w2;   td.dst[7] = w2T;                        td.Rr[7] = 1368; td.Cc[7] = 512;  td.RrPad[7] = KP2;  td.CcPad[7] = 512;
  td.svec[5] = n2w;   // fold rmsnorm2 weight into w1^T
  td.svec[6] = n2w;   // fold rmsnorm2 weight into w3^T
  int tot = 0;
  for (int i = 0; i < 8; ++i) {
    td.gw[i] = (td.CcPad[i] + 63) / 64;
    int gh = (td.RrPad[i] + 63) / 64;
    td.start[i] = tot;
    tot += td.gw[i] * gh;
  }
  td.start[8] = tot;

  prep_kernel<<<tot + NRMS + 1, 256, 0, stream>>>(td, x, n1w, mask, Wdt, dtb, Alog, xnb, dt, la, rs, tot);
  gemm_kernel<<<16 * 48, 256, 0, stream>>>(xnb, WallT, P, BSn, PSTR, Dn);
  chunk_state_kernel<<<NSCAN, 256, 0, stream>>>(P, dt, la, Sbuf, ecL);
  intra_inter_gate_kernel<<<NSCAN, 256, 0, stream>>>(P, dt, la, Sbuf, ecL, Dsk, y2b);
  gemm64_ep_kernel<1><<<32 * 8, 256, 0, stream>>>(y2b, WoutT, x, mask, xres, xresb, rs, BSn, Dn, DINn);
  gemm64g_kernel<<<32 * (KP2 / 64), 256, 0, stream>>>(xresb, rs, w13T, gatedb, BSn, Dn);
  gemm64_ep_kernel<2><<<32 * 8, 256, 0, stream>>>(gatedb, w2T, xres, mask, (float*)d_out, nullptr, rs, BSn, Dn, KP2);
}

// Round 15
// 182.544 us; speedup vs baseline: 1.0400x; 1.0400x over previous
//
#include <hip/hip_runtime.h>
#include <hip/hip_bf16.h>
#include <math.h>

#define Bn 4
#define Sn 512
#define Dn 512
#define DINn 1024
#define Hn 16
#define Pn 64
#define RNn 128
#define DFFn 1368
#define KP2 1408      // w2 K pad / w13T half-stride (BK multiple)
#define BSn (Bn*Sn)
#define CH 64
#define NCH (Sn/CH)   // 8
#define PSTR 6144     // fused proj row stride: [z(1024) | u(1024) | B(2048) | C(2048)]
#define FPAD 2816     // w13T rows: [w1^T pad->1408 | w3^T pad->1408]
#define NSCAN (Bn*NCH*Hn)  // 512 scan blocks
#define NRMS 512      // rmsnorm blocks (4 rows each: 1 row per wave, 4 waves/block)

typedef __attribute__((ext_vector_type(8))) short short8;
typedef __attribute__((ext_vector_type(4))) float f32x4;
typedef __attribute__((ext_vector_type(4))) short short4v;

static __device__ __forceinline__ float bf2f(__hip_bfloat16 v){return __bfloat162float(v);}
static __device__ __forceinline__ __hip_bfloat16 f2bf(float v){return __float2bfloat16(v);}
static __device__ __forceinline__ short f2bfs(float v){ __hip_bfloat16 b=f2bf(v); short s; __builtin_memcpy(&s,&b,2); return s; }
static __device__ __forceinline__ float bfs2f(short s){ __hip_bfloat16 b; __builtin_memcpy(&b,&s,2); return bf2f(b); }

// XCD-aware block swizzle (T1): grid must be a multiple of 8; q = nwg/8.
static __device__ __forceinline__ int xcd_swz(int bid, int q) {
  return (bid & 7) * q + (bid >> 3);
}

// async global->LDS, 16B per lane. LDS dest is wave-uniform base + lane*16 (HW).
typedef const __attribute__((address_space(1))) unsigned int* gas1_u32p;
typedef __attribute__((address_space(3))) unsigned int* gas3_u32p;
static __device__ __forceinline__ void gl_lds16(const void* g, void* l) {
  __builtin_amdgcn_global_load_lds((gas1_u32p)g, (gas3_u32p)l, 16, 0, 0);
}

// ---------------- transpose job table + tile body (64x64 tiles, float4 loads) ----------------
struct T8 {
  const float* src[8];
  const float* svec[8];     // optional per-orig-row scale (n2w fold), nullptr = 1
  __hip_bfloat16* dst[8];
  int Rr[8], Cc[8], RrPad[8], CcPad[8], gw[8];
  int start[9];
};

static __device__ __forceinline__ void transpose_tile(const T8& d, int bid, int t,
                                                      float (*tile)[65]) {
  int i = 0;
#pragma unroll
  for (int k = 1; k < 8; ++k) if (bid >= d.start[k]) i = k;
  int rel = bid - d.start[i];
  int gx = rel % d.gw[i], gy = rel / d.gw[i];
  const float* in = d.src[i];
  const float* sv = d.svec[i];
  __hip_bfloat16* out = d.dst[i];
  int Rr = d.Rr[i], Cc = d.Cc[i], RrPad = d.RrPad[i], CcPad = d.CcPad[i];
  int tx = t & 15, ty = t >> 4;
#pragma unroll
  for (int i4 = 0; i4 < 4; ++i4) {
    int r = gy * 64 + ty + i4 * 16;
    int c0 = gx * 64 + tx * 4;
    f32x4 v = (f32x4){0.f, 0.f, 0.f, 0.f};
    if (r < Rr && c0 + 3 < Cc) v = *(const f32x4*)(in + (size_t)r * Cc + c0);
    tile[ty + i4 * 16][tx * 4 + 0] = v[0];
    tile[ty + i4 * 16][tx * 4 + 1] = v[1];
    tile[ty + i4 * 16][tx * 4 + 2] = v[2];
    tile[ty + i4 * 16][tx * 4 + 3] = v[3];
  }
  __syncthreads();
#pragma unroll
  for (int i4 = 0; i4 < 4; ++i4) {
    int r2 = gx * 64 + ty + i4 * 16;
    int c2 = gy * 64 + tx * 4;
    if (r2 < CcPad && c2 + 3 < RrPad) {
      int k = ty + i4 * 16;
      float s0 = sv ? sv[c2 + 0] : 1.f;
      float s1 = sv ? sv[c2 + 1] : 1.f;
      float s2 = sv ? sv[c2 + 2] : 1.f;
      float s3 = sv ? sv[c2 + 3] : 1.f;
      short4v o;
      o.x = f2bfs(tile[tx * 4 + 0][k] * s0);
      o.y = f2bfs(tile[tx * 4 + 1][k] * s1);
      o.z = f2bfs(tile[tx * 4 + 2][k] * s2);
      o.w = f2bfs(tile[tx * 4 + 3][k] * s3);
      *(short4v*)((short*)out + (size_t)r2 * RrPad + c2) = o;
    }
  }
}

// ---------------- prep: transposes + wave-per-row rmsnorm1+dt + zero(rs) ---------------------
__global__ __launch_bounds__(256) void prep_kernel(
    T8 d, const float* __restrict__ x, const float* __restrict__ w,
    const float* __restrict__ mask, const float* __restrict__ Wdt,
    const float* __restrict__ dtb, const float* __restrict__ Alog,
    __hip_bfloat16* __restrict__ outb, float* __restrict__ dt,
    float* __restrict__ la, float* __restrict__ rs, int tstart) {
  __shared__ __align__(16) char smem[40960];
  int bid = blockIdx.x, t = threadIdx.x;
  if (bid < tstart) {
    transpose_tile(d, bid, t, (float(*)[65])smem);
  } else if (bid - tstart < NRMS) {
    float* wdtS = (float*)smem;                    // [512][16] f32
    float* xsS  = (float*)(smem + 32768);          // [4][512] f32 (per-wave exclusive)
#pragma unroll
    for (int i = 0; i < 8; ++i) {
      int idx = t + i * 256;
      *(f32x4*)&wdtS[idx * 4] = *(const f32x4*)&Wdt[idx * 4];
    }
    __syncthreads();
    int wv = t >> 6, lane = t & 63;
    int row = (bid - tstart) * 4 + wv;
    const float* xr = x + (size_t)row * Dn;
    f32x4 v0 = *(const f32x4*)(xr + lane * 4);
    f32x4 v1 = *(const f32x4*)(xr + 256 + lane * 4);
    float ss = v0[0]*v0[0] + v0[1]*v0[1] + v0[2]*v0[2] + v0[3]*v0[3]
             + v1[0]*v1[0] + v1[1]*v1[1] + v1[2]*v1[2] + v1[3]*v1[3];
#pragma unroll
    for (int o = 32; o > 0; o >>= 1) ss += __shfl_xor(ss, o);
    float sc = rsqrtf(ss * (1.f / Dn) + 1e-6f) * mask[row];
    f32x4 w0 = *(const f32x4*)(w + lane * 4);
    f32x4 w1 = *(const f32x4*)(w + 256 + lane * 4);
    f32x4 o0, o1;
#pragma unroll
    for (int j = 0; j < 4; ++j) { o0[j] = v0[j] * sc * w0[j]; o1[j] = v1[j] * sc * w1[j]; }
    short4v b0, b1;
    b0.x = f2bfs(o0[0]); b0.y = f2bfs(o0[1]); b0.z = f2bfs(o0[2]); b0.w = f2bfs(o0[3]);
    b1.x = f2bfs(o1[0]); b1.y = f2bfs(o1[1]); b1.z = f2bfs(o1[2]); b1.w = f2bfs(o1[3]);
    *(short4v*)((short*)outb + (size_t)row * Dn + lane * 4) = b0;
    *(short4v*)((short*)outb + (size_t)row * Dn + 256 + lane * 4) = b1;
    *(f32x4*)&xsS[wv * 512 + lane * 4] = o0;
    *(f32x4*)&xsS[wv * 512 + 256 + lane * 4] = o1;
    int h = lane >> 2, j = lane & 3;
    float s = 0.f;
#pragma unroll 8
    for (int kk = 0; kk < 128; ++kk) {
      int k = j + kk * 4;
      s = fmaf(xsS[wv * 512 + k], wdtS[k * Hn + h], s);
    }
    s += __shfl_down(s, 2, 4);
    s += __shfl_down(s, 1, 4);
    if (j == 0) {
      float v = s + dtb[h];
      float sp = (v > 20.f) ? v : log1pf(expf(v));
      float Ah = expf(Alog[h]);
      dt[(size_t)row * Hn + h] = sp;
      la[(size_t)row * Hn + h] = -Ah * sp;
    }
  } else {
    *(f32x4*)&rs[t * 8]     = (f32x4){0.f, 0.f, 0.f, 0.f};
    *(f32x4*)&rs[t * 8 + 4] = (f32x4){0.f, 0.f, 0.f, 0.f};
  }
}

// ---------------- GEMM 128x128, BK=32, gl_lds staging, XCD swizzle (proj) --------------------
__global__ __launch_bounds__(256) void gemm_kernel(
    const __hip_bfloat16* __restrict__ A, const __hip_bfloat16* __restrict__ BT,
    __hip_bfloat16* __restrict__ C, int M, int N, int K) {
  __shared__ short As[2][4096];
  __shared__ short Bs[2][4096];
  int mblocks = M >> 7;
  int wg = xcd_swz(blockIdx.x, (int)gridDim.x >> 3);
  int m0 = (wg % mblocks) * 128, n0 = (wg / mblocks) * 128;
  int t = threadIdx.x;
  int lane = t & 63, wv = t >> 6;
  int wm = (wv & 1) * 64, wn = (wv >> 1) * 64;
  f32x4 acc[4][4];
#pragma unroll
  for (int i = 0; i < 4; ++i)
#pragma unroll
    for (int j = 0; j < 4; ++j) acc[i][j] = (f32x4){0.f, 0.f, 0.f, 0.f};
  const short* Ag = (const short*)A;
  const short* Bg = (const short*)BT;
  int r0 = t >> 2, p = t & 3;
  int q0 = (p - (r0 >> 1)) & 3;
  int r1 = r0 + 64;
  int q1 = (p - (r1 >> 1)) & 3;
  const short* Asrc0 = Ag + (size_t)(m0 + r0) * K + 8 * q0;
  const short* Asrc1 = Ag + (size_t)(m0 + r1) * K + 8 * q1;
  const short* Bsrc0 = Bg + (size_t)(n0 + r0) * K + 8 * q0;
  const short* Bsrc1 = Bg + (size_t)(n0 + r1) * K + 8 * q1;
  int fr = lane & 15, fq = lane >> 4;
  int kTiles = K >> 5;
  auto stage = [&](int buf, int k0) {
    gl_lds16(Asrc0 + k0, &As[buf][wv * 512]);
    gl_lds16(Asrc1 + k0, &As[buf][2048 + wv * 512]);
    gl_lds16(Bsrc0 + k0, &Bs[buf][wv * 512]);
    gl_lds16(Bsrc1 + k0, &Bs[buf][2048 + wv * 512]);
  };
  auto domfma = [&](int buf) {
    short8 af[4], bfr[4];
#pragma unroll
    for (int i = 0; i < 4; ++i) {
      int rr = wm + i * 16 + fr;
      af[i] = *(const short8*)&As[buf][rr * 32 + (((rr >> 1) + fq) & 3) * 8];
    }
#pragma unroll
    for (int i = 0; i < 4; ++i) {
      int rr = wn + i * 16 + fr;
      bfr[i] = *(const short8*)&Bs[buf][rr * 32 + (((rr >> 1) + fq) & 3) * 8];
    }
#pragma unroll
    for (int mi = 0; mi < 4; ++mi)
#pragma unroll
      for (int ni = 0; ni < 4; ++ni)
        acc[mi][ni] = __builtin_amdgcn_mfma_f32_16x16x32_bf16(af[mi], bfr[ni], acc[mi][ni], 0, 0, 0);
  };
  stage(0, 0);
  for (int kt = 0; kt < kTiles; ++kt) {
    int buf = kt & 1;
    __syncthreads();
    if (kt + 1 < kTiles) stage(buf ^ 1, (kt + 1) << 5);
    domfma(buf);
  }
  int fq4 = (lane >> 4) * 4;
#pragma unroll
  for (int mi = 0; mi < 4; ++mi)
#pragma unroll
    for (int ni = 0; ni < 4; ++ni) {
      int col = n0 + wn + ni * 16 + fr;
      if (col < N) {
        int rowb = m0 + wm + mi * 16 + fq4;
#pragma unroll
        for (int r = 0; r < 4; ++r)
          C[(size_t)(rowb + r) * N + col] = f2bf(acc[mi][ni][r]);
      }
    }
}

// ---------------- GEMM 64x64, BK=64, dbuf x2; XCD swizzle; MODE1: +row-sumsq + bf16 copy -----
template <int MODE>
__global__ __launch_bounds__(256) void gemm64_ep_kernel(
    const __hip_bfloat16* __restrict__ A, const __hip_bfloat16* __restrict__ BT,
    const float* __restrict__ aux, const float* __restrict__ mask,
    float* __restrict__ out, __hip_bfloat16* __restrict__ outb,
    float* __restrict__ rs, int M, int N, int K) {
  __shared__ short As[2][64][72];
  __shared__ short Bs[2][64][72];
  int mblocks = M >> 6;
  int wg = xcd_swz(blockIdx.x, (int)gridDim.x >> 3);
  int m0 = (wg % mblocks) * 64, n0 = (wg / mblocks) * 64;
  int t = threadIdx.x;
  int lane = t & 63, wv = t >> 6;
  int wm = (wv & 1) * 32, wn = (wv >> 1) * 32;
  f32x4 acc[2][2];
#pragma unroll
  for (int i = 0; i < 2; ++i)
#pragma unroll
    for (int j = 0; j < 2; ++j) acc[i][j] = (f32x4){0.f, 0.f, 0.f, 0.f};
  const short* Ag = (const short*)A;
  const short* Bg = (const short*)BT;
  int sr = t >> 2;
  int sc = (t & 3) * 16;
  const short* Ap = Ag + (size_t)(m0 + sr) * K + sc;
  const short* Bp = Bg + (size_t)(n0 + sr) * K + sc;
  int fr = lane & 15, fq = (lane >> 4) * 8;
  int kTiles = K >> 6;
  short8 a0A = 0, a1A = 0, b0A = 0, b1A = 0;
  short8 a0B = 0, a1B = 0, b0B = 0, b1B = 0;
  auto loadA = [&](int k0) {
    a0A = *(const short8*)(Ap + k0);
    a1A = *(const short8*)(Ap + k0 + 8);
    b0A = *(const short8*)(Bp + k0);
    b1A = *(const short8*)(Bp + k0 + 8);
  };
  auto loadB = [&](int k0) {
    a0B = *(const short8*)(Ap + k0);
    a1B = *(const short8*)(Ap + k0 + 8);
    b0B = *(const short8*)(Bp + k0);
    b1B = *(const short8*)(Bp + k0 + 8);
  };
  auto storeA = [&](int buf) {
    *(short8*)&As[buf][sr][sc] = a0A;
    *(short8*)&As[buf][sr][sc + 8] = a1A;
    *(short8*)&Bs[buf][sr][sc] = b0A;
    *(short8*)&Bs[buf][sr][sc + 8] = b1A;
  };
  auto storeB = [&](int buf) {
    *(short8*)&As[buf][sr][sc] = a0B;
    *(short8*)&As[buf][sr][sc + 8] = a1B;
    *(short8*)&Bs[buf][sr][sc] = b0B;
    *(short8*)&Bs[buf][sr][sc + 8] = b1B;
  };
  auto mfma = [&](int buf) {
#pragma unroll
    for (int kk = 0; kk < 2; ++kk) {
      short8 af[2], bfr[2];
#pragma unroll
      for (int i = 0; i < 2; ++i) af[i] = *(const short8*)&As[buf][wm + i * 16 + fr][kk * 32 + fq];
#pragma unroll
      for (int i = 0; i < 2; ++i) bfr[i] = *(const short8*)&Bs[buf][wn + i * 16 + fr][kk * 32 + fq];
#pragma unroll
      for (int mi = 0; mi < 2; ++mi)
#pragma unroll
        for (int ni = 0; ni < 2; ++ni)
          acc[mi][ni] = __builtin_amdgcn_mfma_f32_16x16x32_bf16(af[mi], bfr[ni], acc[mi][ni], 0, 0, 0);
    }
  };
  loadA(0);
  storeA(0);
  loadA(64);
  __syncthreads();
  for (int kt = 0; kt < kTiles; kt += 2) {
    storeA(1);
    if (kt + 2 < kTiles) loadB((kt + 2) << 6);
    mfma(0);
    __syncthreads();
    if (kt + 2 < kTiles) storeB(0);
    if (kt + 3 < kTiles) loadA((kt + 3) << 6);
    mfma(1);
    __syncthreads();
  }
  int fq4 = (lane >> 4) * 4;
  float rsum[2][4];
#pragma unroll
  for (int mi = 0; mi < 2; ++mi)
#pragma unroll
    for (int r = 0; r < 4; ++r) rsum[mi][r] = 0.f;
#pragma unroll
  for (int mi = 0; mi < 2; ++mi)
#pragma unroll
    for (int ni = 0; ni < 2; ++ni) {
      int col = n0 + wn + ni * 16 + fr;
#pragma unroll
      for (int r = 0; r < 4; ++r) {
        int row = m0 + wm + mi * 16 + fq4 + r;
        float m = mask[row];
        size_t a = (size_t)row * N + col;
        float v = acc[mi][ni][r];
        if (MODE == 1) {
          float ov = aux[a] + v * m;
          out[a] = ov;
          outb[a] = f2bf(ov);
          rsum[mi][r] += ov * ov;
        } else {
          out[a] = (aux[a] + v) * m;
        }
      }
    }
  if (MODE == 1) {
#pragma unroll
    for (int mi = 0; mi < 2; ++mi)
#pragma unroll
      for (int r = 0; r < 4; ++r) {
        float s = rsum[mi][r];
#pragma unroll
        for (int o = 8; o > 0; o >>= 1) s += __shfl_xor(s, o);
        if ((lane & 15) == 0) {
          int row = m0 + wm + mi * 16 + fq4 + r;
          atomicAdd(&rs[row], s);
        }
      }
  }
}

// ---------------- fused FFN GEMM 64x64: symmetric w13T, silu-gate, no edge branch ------------
__global__ __launch_bounds__(256) void gemm64g_kernel(
    const __hip_bfloat16* __restrict__ A, const float* __restrict__ rs,
    const __hip_bfloat16* __restrict__ BT, __hip_bfloat16* __restrict__ G,
    int M, int K) {
  __shared__ short As[2][64][72];
  __shared__ short B1s[2][64][72];
  __shared__ short B3s[2][64][72];
  __shared__ float ssc[64];
  int mblocks = M >> 6;
  int wg = xcd_swz(blockIdx.x, (int)gridDim.x >> 3);
  int m0 = (wg % mblocks) * 64, n0 = (wg / mblocks) * 64;
  int t = threadIdx.x;
  int lane = t & 63, wv = t >> 6;
  int wm = (wv & 1) * 32, wn = (wv >> 1) * 32;
  f32x4 acc1[2][2], acc3[2][2];
#pragma unroll
  for (int i = 0; i < 2; ++i)
#pragma unroll
    for (int j = 0; j < 2; ++j) {
      acc1[i][j] = (f32x4){0.f, 0.f, 0.f, 0.f};
      acc3[i][j] = (f32x4){0.f, 0.f, 0.f, 0.f};
    }
  const short* Ag = (const short*)A;
  const short* Bg = (const short*)BT;
  int sr = t >> 2;
  int sc = (t & 3) * 16;
  const short* Ap  = Ag + (size_t)(m0 + sr) * K + sc;
  const short* B1p = Bg + (size_t)(n0 + sr) * K + sc;
  const short* B3p = Bg + (size_t)(KP2 + n0 + sr) * K + sc;
  int fr = lane & 15, fq = (lane >> 4) * 8;
  int kTiles = K >> 6;
  if (t < 64) ssc[t] = rsqrtf(rs[m0 + t] * (1.f / Dn) + 1e-6f);
  short8 a0A = 0, a1A = 0, c0A = 0, c1A = 0, d0A = 0, d1A = 0;
  short8 a0B = 0, a1B = 0, c0B = 0, c1B = 0, d0B = 0, d1B = 0;
  auto loadA = [&](int k0) {
    a0A = *(const short8*)(Ap + k0);
    a1A = *(const short8*)(Ap + k0 + 8);
    c0A = *(const short8*)(B1p + k0);
    c1A = *(const short8*)(B1p + k0 + 8);
    d0A = *(const short8*)(B3p + k0);
    d1A = *(const short8*)(B3p + k0 + 8);
  };
  auto loadB = [&](int k0) {
    a0B = *(const short8*)(Ap + k0);
    a1B = *(const short8*)(Ap + k0 + 8);
    c0B = *(const short8*)(B1p + k0);
    c1B = *(const short8*)(B1p + k0 + 8);
    d0B = *(const short8*)(B3p + k0);
    d1B = *(const short8*)(B3p + k0 + 8);
  };
  auto storeA = [&](int buf) {
    *(short8*)&As[buf][sr][sc] = a0A;
    *(short8*)&As[buf][sr][sc + 8] = a1A;
    *(short8*)&B1s[buf][sr][sc] = c0A;
    *(short8*)&B1s[buf][sr][sc + 8] = c1A;
    *(short8*)&B3s[buf][sr][sc] = d0A;
    *(short8*)&B3s[buf][sr][sc + 8] = d1A;
  };
  auto storeB = [&](int buf) {
    *(short8*)&As[buf][sr][sc] = a0B;
    *(short8*)&As[buf][sr][sc + 8] = a1B;
    *(short8*)&B1s[buf][sr][sc] = c0B;
    *(short8*)&B1s[buf][sr][sc + 8] = c1B;
    *(short8*)&B3s[buf][sr][sc] = d0B;
    *(short8*)&B3s[buf][sr][sc + 8] = d1B;
  };
  auto mfma = [&](int buf) {
#pragma unroll
    for (int kk = 0; kk < 2; ++kk) {
      short8 af[2], b1f[2], b3f[2];
#pragma unroll
      for (int i = 0; i < 2; ++i) af[i]  = *(const short8*)&As[buf][wm + i * 16 + fr][kk * 32 + fq];
#pragma unroll
      for (int i = 0; i < 2; ++i) b1f[i] = *(const short8*)&B1s[buf][wn + i * 16 + fr][kk * 32 + fq];
#pragma unroll
      for (int i = 0; i < 2; ++i) b3f[i] = *(const short8*)&B3s[buf][wn + i * 16 + fr][kk * 32 + fq];
#pragma unroll
      for (int mi = 0; mi < 2; ++mi)
#pragma unroll
        for (int ni = 0; ni < 2; ++ni) {
          acc1[mi][ni] = __builtin_amdgcn_mfma_f32_16x16x32_bf16(af[mi], b1f[ni], acc1[mi][ni], 0, 0, 0);
          acc3[mi][ni] = __builtin_amdgcn_mfma_f32_16x16x32_bf16(af[mi], b3f[ni], acc3[mi][ni], 0, 0, 0);
        }
    }
  };
  loadA(0);
  storeA(0);
  loadA(64);
  __syncthreads();
  for (int kt = 0; kt < kTiles; kt += 2) {
    storeA(1);
    if (kt + 2 < kTiles) loadB((kt + 2) << 6);
    mfma(0);
    __syncthreads();
    if (kt + 2 < kTiles) storeB(0);
    if (kt + 3 < kTiles) loadA((kt + 3) << 6);
    mfma(1);
    __syncthreads();
  }
  int fq4 = (lane >> 4) * 4;
#pragma unroll
  for (int mi = 0; mi < 2; ++mi)
#pragma unroll
    for (int ni = 0; ni < 2; ++ni) {
      int col = n0 + wn + ni * 16 + fr;
#pragma unroll
      for (int r = 0; r < 4; ++r) {
        int rloc = wm + mi * 16 + fq4 + r;
        float scl = ssc[rloc];
        float h1v = acc1[mi][ni][r] * scl;
        float sil = h1v / (1.f + __expf(-h1v));
        float g = sil * (acc3[mi][ni][r] * scl);
        G[(size_t)(m0 + rloc) * KP2 + col] = f2bf(g);
      }
    }
}

// ---------------- chunk_state: B,u -> S (transposed [p][rn]) + ecL ---------------------------
__global__ __launch_bounds__(256) void chunk_state_kernel(
    const __hip_bfloat16* __restrict__ P, const float* __restrict__ dt,
    const float* __restrict__ la, __hip_bfloat16* __restrict__ Sbuf,
    float* __restrict__ ecL) {
  int id = blockIdx.x;
  int h = id & 15, c = (id >> 4) & 7, b = id >> 7;
  int t = threadIdx.x, lane = t & 63, wv = t >> 6;
  __shared__ __align__(16) char smem[45824];
  short* sB   = (short*)smem;                 // [64][136]
  short* sUD  = (short*)(smem + 17408);       // [64*72] u*dt transposed [p][s]
  short* sBwT = (short*)(smem + 26624);       // [128][72] weighted B^T [rn][s]
  float* scum = (float*)(smem + 45056);
  float* sws  = scum + 64;
  float* sdt  = sws + 64;
  int row0 = b * Sn + c * CH;
  const short* Pb = (const short*)P;
#pragma unroll
  for (int i = 0; i < 4; ++i) {
    int idx = t + i * 256;
    int r = idx >> 4, kk = (idx & 15) * 8;
    *(short8*)&sB[r * 136 + kk] = *(const short8*)(Pb + (size_t)(row0 + r) * PSTR + 2048 + h * 128 + kk);
  }
  if (t < 64) { sdt[t] = dt[(size_t)(row0 + t) * Hn + h]; scum[t] = la[(size_t)(row0 + t) * Hn + h]; }
  __syncthreads();
  if (wv == 0) {
    float v = scum[lane];
#pragma unroll
    for (int o = 1; o < 64; o <<= 1) { float n = __shfl_up(v, o); if (lane >= o) v += n; }
    float c63 = __shfl(v, 63);
    sws[lane] = __expf(c63 - v);
    if (lane == 0) ecL[(b * NCH + c) * Hn + h] = __expf(c63);
  }
#pragma unroll
  for (int i = 0; i < 2; ++i) {
    int idx = t + i * 256;
    int s = idx >> 3, pc = (idx & 7) * 8;
    short8 uv = *(const short8*)(Pb + (size_t)(row0 + s) * PSTR + 1024 + h * 64 + pc);
    float dv = sdt[s];
#pragma unroll
    for (int j = 0; j < 8; ++j) sUD[(pc + j) * 72 + s] = f2bfs(bfs2f(uv[j]) * dv);
  }
  __syncthreads();
#pragma unroll
  for (int i = 0; i < 32; ++i) {
    int idx = t + i * 256;
    int rn = idx >> 6, s = idx & 63;
    sBwT[rn * 72 + s] = f2bfs(bfs2f(sB[s * 136 + rn]) * sws[s]);
  }
  __syncthreads();
  int fr = lane & 15, fq = (lane >> 4) * 8, q4 = (lane >> 4) * 4;
#pragma unroll
  for (int mt0 = 0; mt0 < 2; ++mt0) {
    int mt = wv * 2 + mt0;
    short8 ab[2];
#pragma unroll
    for (int k = 0; k < 2; ++k) ab[k] = *(short8*)&sBwT[(16 * mt + fr) * 72 + k * 32 + fq];
#pragma unroll
    for (int j = 0; j < 4; ++j) {
      f32x4 acc = (f32x4){0.f, 0.f, 0.f, 0.f};
#pragma unroll
      for (int k = 0; k < 2; ++k) {
        short8 bf = *(short8*)&sUD[(16 * j + fr) * 72 + k * 32 + fq];
        acc = __builtin_amdgcn_mfma_f32_16x16x32_bf16(ab[k], bf, acc, 0, 0, 0);
      }
      int pp = 16 * j + fr;
      int rn0 = 16 * mt + q4;
      short4v o;
      o.x = f2bfs(acc[0]); o.y = f2bfs(acc[1]); o.z = f2bfs(acc[2]); o.w = f2bfs(acc[3]);
      *(short4v*)&((short*)Sbuf)[((size_t)((b * NCH + c) * Hn + h) * 64 + pp) * 128 + rn0] = o;
    }
  }
}

// ---------------- intra + cross-chunk prefix + inter + gate (single-pass, ys in regs) --------
__global__ __launch_bounds__(256) void intra_inter_gate_kernel(
    const __hip_bfloat16* __restrict__ P, const float* __restrict__ dt,
    const float* __restrict__ la, const __hip_bfloat16* __restrict__ Sbuf,
    const float* __restrict__ ecL, const float* __restrict__ Dsk,
    __hip_bfloat16* __restrict__ y2b) {
  int id = blockIdx.x;
  int h = id & 15, c = (id >> 4) & 7, b = id >> 7;
  int t = threadIdx.x, lane = t & 63, wv = t >> 6;
  __shared__ __align__(16) char smem[54016];
  short* sCB = (short*)smem;
  short* sB  = (short*)(smem + 17408);
  short* sUD = (short*)(smem + 34816);
  short* sG  = (short*)(smem + 44032);
  short* sHt = (short*)(smem + 34816);        // aliases sUD+sG after ys
  short* sz  = sB;                            // [64][64] bytes [17408,25600) -- dead sB
  short* su  = sB + 4096;                     // [64][64] bytes [25600,33792) -- dead sB
  float* scum = (float*)(smem + 53248);
  float* sdt  = scum + 64;
  int row0 = b * Sn + c * CH;
  const short* Pb = (const short*)P;
#pragma unroll
  for (int i = 0; i < 4; ++i) {
    int idx = t + i * 256;
    int r = idx >> 4, kk = (idx & 15) * 8;
    *(short8*)&sCB[r * 136 + kk] = *(const short8*)(Pb + (size_t)(row0 + r) * PSTR + 4096 + h * 128 + kk);
    *(short8*)&sB [r * 136 + kk] = *(const short8*)(Pb + (size_t)(row0 + r) * PSTR + 2048 + h * 128 + kk);
  }
  if (t < 64) { sdt[t] = dt[(size_t)(row0 + t) * Hn + h]; scum[t] = la[(size_t)(row0 + t) * Hn + h]; }
  __syncthreads();
  if (wv == 0) {
    float v = scum[lane];
#pragma unroll
    for (int o = 1; o < 64; o <<= 1) { float n = __shfl_up(v, o); if (lane >= o) v += n; }
    scum[lane] = v;
  }
#pragma unroll
  for (int i = 0; i < 2; ++i) {
    int idx = t + i * 256;
    int s = idx >> 3, pc = (idx & 7) * 8;
    short8 uv = *(const short8*)(Pb + (size_t)(row0 + s) * PSTR + 1024 + h * 64 + pc);
    float dv = sdt[s];
#pragma unroll
    for (int j = 0; j < 8; ++j) sUD[(pc + j) * 72 + s] = f2bfs(bfs2f(uv[j]) * dv);
  }
  __syncthreads();
  int fr = lane & 15, fq = (lane >> 4) * 8, q4 = (lane >> 4) * 4;
  {
    short8 af[4];
#pragma unroll
    for (int k = 0; k < 4; ++k) af[k] = *(short8*)&sCB[(16 * wv + fr) * 136 + k * 32 + fq];
#pragma unroll
    for (int j = 0; j < 4; ++j) {
      f32x4 acc = (f32x4){0.f, 0.f, 0.f, 0.f};
#pragma unroll
      for (int k = 0; k < 4; ++k) {
        short8 bf = *(short8*)&sB[(16 * j + fr) * 136 + k * 32 + fq];
        acc = __builtin_amdgcn_mfma_f32_16x16x32_bf16(af[k], bf, acc, 0, 0, 0);
      }
      int ss = 16 * j + fr;
      float cs = scum[ss];
#pragma unroll
      for (int r = 0; r < 4; ++r) {
        int tt = 16 * wv + q4 + r;
        float w = (ss <= tt) ? __expf(scum[tt] - cs) : 0.f;
        sG[tt * 72 + ss] = f2bfs(acc[r] * w);
      }
    }
  }
  __syncthreads();
  f32x4 ysr[4];
  {
    short8 ag[2];
#pragma unroll
    for (int k = 0; k < 2; ++k) ag[k] = *(short8*)&sG[(16 * wv + fr) * 72 + k * 32 + fq];
#pragma unroll
    for (int j = 0; j < 4; ++j) {
      f32x4 acc = (f32x4){0.f, 0.f, 0.f, 0.f};
#pragma unroll
      for (int k = 0; k < 2; ++k) {
        short8 bf = *(short8*)&sUD[(16 * j + fr) * 72 + k * 32 + fq];
        acc = __builtin_amdgcn_mfma_f32_16x16x32_bf16(ag[k], bf, acc, 0, 0, 0);
      }
      ysr[j] = acc;
    }
  }
#pragma unroll
  for (int i = 0; i < 2; ++i) {
    int idx = t + i * 256;
    int r = idx >> 3, pc = (idx & 7) * 8;
    *(short8*)&sz[r * 64 + pc] = *(const short8*)(Pb + (size_t)(row0 + r) * PSTR + h * 64 + pc);
    *(short8*)&su[r * 64 + pc] = *(const short8*)(Pb + (size_t)(row0 + r) * PSTR + 1024 + h * 64 + pc);
  }
  float hacc[32];
#pragma unroll
  for (int jj = 0; jj < 32; ++jj) hacc[jj] = 0.f;
  if (c > 0) {
    const short* Sb = (const short*)Sbuf;
    float wrun = 1.f;
    for (int cp = c - 1; cp >= 0; --cp) {
      size_t base = ((size_t)((b * NCH + cp) * Hn + h)) * 8192 + (size_t)t * 32;
#pragma unroll
      for (int v4 = 0; v4 < 4; ++v4) {
        short8 sv = *(const short8*)(Sb + base + v4 * 8);
#pragma unroll
        for (int jj = 0; jj < 8; ++jj)
          hacc[v4 * 8 + jj] = fmaf(wrun, bfs2f(sv[jj]), hacc[v4 * 8 + jj]);
      }
      wrun *= ecL[(size_t)((b * NCH + cp) * Hn + h)];
    }
  }
  __syncthreads();
  if (c > 0) {
    int pp = t >> 2, rn0 = (t & 3) * 32;
#pragma unroll
    for (int v4 = 0; v4 < 4; ++v4) {
      short8 o;
#pragma unroll
      for (int jj = 0; jj < 8; ++jj) o[jj] = f2bfs(hacc[v4 * 8 + jj]);
      *(short8*)&sHt[pp * 136 + rn0 + v4 * 8] = o;
    }
  }
  __syncthreads();
  f32x4 acc[4];
#pragma unroll
  for (int j = 0; j < 4; ++j) acc[j] = (f32x4){0.f, 0.f, 0.f, 0.f};
  if (c > 0) {
    short8 af[4];
#pragma unroll
    for (int k = 0; k < 4; ++k) af[k] = *(short8*)&sCB[(16 * wv + fr) * 136 + k * 32 + fq];
#pragma unroll
    for (int j = 0; j < 4; ++j)
#pragma unroll
      for (int k = 0; k < 4; ++k) {
        short8 bf = *(short8*)&sHt[(16 * j + fr) * 136 + k * 32 + fq];
        acc[j] = __builtin_amdgcn_mfma_f32_16x16x32_bf16(af[k], bf, acc[j], 0, 0, 0);
      }
  }
  float dsk = Dsk[h];
#pragma unroll
  for (int j = 0; j < 4; ++j) {
    int col = 16 * j + fr;
#pragma unroll
    for (int r = 0; r < 4; ++r) {
      int tt = 16 * wv + q4 + r;
      size_t a = (size_t)(row0 + tt) * DINn + h * 64 + col;
      float val = ysr[j][r];
      if (c > 0) val += __expf(scum[tt]) * acc[j][r];
      float uu = bfs2f(su[tt * 64 + col]);
      float zz = bfs2f(sz[tt * 64 + col]);
      float sil = zz / (1.f + __expf(-zz));
      y2b[a] = f2bf((val + uu * dsk) * sil);
    }
  }
}

extern "C" void kernel_launch(void* const* d_in, const int* in_sizes, int n_in,
                              void* d_out, int out_size, void* d_ws, size_t ws_size,
                              hipStream_t stream) {
  const float* x    = (const float*)d_in[0];
  const float* mask = (const float*)d_in[1];
  const float* n1w  = (const float*)d_in[2];
  const float* n2w  = (const float*)d_in[3];
  const float* Wz   = (const float*)d_in[4];
  const float* Wx   = (const float*)d_in[5];
  const float* Wb   = (const float*)d_in[6];
  const float* Wc   = (const float*)d_in[7];
  const float* Wdt  = (const float*)d_in[8];
  const float* dtb  = (const float*)d_in[9];
  const float* Alog = (const float*)d_in[10];
  const float* Dsk  = (const float*)d_in[11];
  const float* Wout = (const float*)d_in[12];
  const float* w1   = (const float*)d_in[13];
  const float* w2   = (const float*)d_in[14];
  const float* w3   = (const float*)d_in[15];

  char* ws = (char*)d_ws;
  size_t off = 0;
  auto alloc = [&](size_t bytes) {
    char* p = ws + off;
    off += (bytes + 255) & ~(size_t)255;
    return p;
  };
  __hip_bfloat16* xnb = (__hip_bfloat16*)alloc((size_t)BSn * Dn * 2);
  __hip_bfloat16* P = (__hip_bfloat16*)alloc((size_t)BSn * PSTR * 2);
  float* dt  = (float*)alloc((size_t)BSn * Hn * 4);
  float* la  = (float*)alloc((size_t)BSn * Hn * 4);
  float* ecL = (float*)alloc((size_t)Bn * NCH * Hn * 4);
  float* rs  = (float*)alloc((size_t)BSn * 4);
  __hip_bfloat16* WallT = (__hip_bfloat16*)alloc((size_t)PSTR * Dn * 2);   // [z|u|B|C]^T
  __hip_bfloat16* WoutT = (__hip_bfloat16*)alloc((size_t)Dn * DINn * 2);
  __hip_bfloat16* w13T  = (__hip_bfloat16*)alloc((size_t)FPAD * Dn * 2);   // [w1^T|pad | w3^T|pad]
  __hip_bfloat16* w2T   = (__hip_bfloat16*)alloc((size_t)Dn * KP2 * 2);    // K-pad 1408
  char* arena = alloc(23200000);
  __hip_bfloat16* Sbuf = (__hip_bfloat16*)arena;                  // 8.4 MB, dead after intra_inter
  __hip_bfloat16* y2b  = (__hip_bfloat16*)(arena + 16777216);     // 4.2 MB
  float* xres          = (float*)arena;                            // 4 MB, aliases Sbuf (after)
  __hip_bfloat16* gatedb = (__hip_bfloat16*)(arena + 4194304);     // 5.8 MB
  __hip_bfloat16* xresb  = (__hip_bfloat16*)(arena + 20971520);    // 2 MB bf16 residual

  // -------- transpose job table (64x64 tiles) --------
  T8 td;
  for (int i = 0; i < 8; ++i) td.svec[i] = nullptr;
  td.src[0] = Wz;   td.dst[0] = WallT;                      td.Rr[0] = 512;  td.Cc[0] = 1024; td.RrPad[0] = 512;  td.CcPad[0] = 1024;
  td.src[1] = Wx;   td.dst[1] = WallT + (size_t)1024 * 512; td.Rr[1] = 512;  td.Cc[1] = 1024; td.RrPad[1] = 512;  td.CcPad[1] = 1024;
  td.src[2] = Wb;   td.dst[2] = WallT + (size_t)2048 * 512; td.Rr[2] = 512;  td.Cc[2] = 2048; td.RrPad[2] = 512;  td.CcPad[2] = 2048;
  td.src[3] = Wc;   td.dst[3] = WallT + (size_t)4096 * 512; td.Rr[3] = 512;  td.Cc[3] = 2048; td.RrPad[3] = 512;  td.CcPad[3] = 2048;
  td.src[4] = Wout; td.dst[4] = WoutT;                      td.Rr[4] = 1024; td.Cc[4] = 512;  td.RrPad[4] = 1024; td.CcPad[4] = 512;
  td.src[5] = w1;   td.dst[5] = w13T;                       td.Rr[5] = 512;  td.Cc[5] = 1368; td.RrPad[5] = 512;  td.CcPad[5] = KP2;
  td.src[6] = w3;   td.dst[6] = w13T + (size_t)KP2 * 512;   td.Rr[6] = 512;  td.Cc[6] = 1368; td.RrPad[6] = 512;  td.CcPad[6] = KP2;
  td.src[7] = w2;   td.dst[7] = w2T;                        td.Rr[7] = 1368; td.Cc[7] = 512;  td.RrPad[7] = KP2;  td.CcPad[7] = 512;
  td.svec[5] = n2w;   // fold rmsnorm2 weight into w1^T
  td.svec[6] = n2w;   // fold rmsnorm2 weight into w3^T
  int tot = 0;
  for (int i = 0; i < 8; ++i) {
    td.gw[i] = (td.CcPad[i] + 63) / 64;
    int gh = (td.RrPad[i] + 63) / 64;
    td.start[i] = tot;
    tot += td.gw[i] * gh;
  }
  td.start[8] = tot;

  prep_kernel<<<tot + NRMS + 1, 256, 0, stream>>>(td, x, n1w, mask, Wdt, dtb, Alog, xnb, dt, la, rs, tot);
  gemm_kernel<<<16 * 48, 256, 0, stream>>>(xnb, WallT, P, BSn, PSTR, Dn);
  chunk_state_kernel<<<NSCAN, 256, 0, stream>>>(P, dt, la, Sbuf, ecL);
  intra_inter_gate_kernel<<<NSCAN, 256, 0, stream>>>(P, dt, la, Sbuf, ecL, Dsk, y2b);
  gemm64_ep_kernel<1><<<32 * 8, 256, 0, stream>>>(y2b, WoutT, x, mask, xres, xresb, rs, BSn, Dn, DINn);
  gemm64g_kernel<<<32 * (KP2 / 64), 256, 0, stream>>>(xresb, rs, w13T, gatedb, BSn, Dn);
  gemm64_ep_kernel<2><<<32 * 8, 256, 0, stream>>>(gatedb, w2T, xres, mask, (float*)d_out, nullptr, rs, BSn, Dn, KP2);
}